// Round 12
// baseline (311.110 us; speedup 1.0000x reference)
//
#include <hip/hip_runtime.h>
#include <cmath>

typedef __bf16 bf16_t;
typedef bf16_t bf16x8 __attribute__((ext_vector_type(8)));
typedef bf16_t bf16x4 __attribute__((ext_vector_type(4)));
typedef float  f32x4  __attribute__((ext_vector_type(4)));
typedef float  f32x16 __attribute__((ext_vector_type(16)));
typedef unsigned int u32x4v __attribute__((ext_vector_type(4)));

#define Bn  4
#define TQn 1024
#define TKn 1024
#define En  1024
#define Hn  16
#define DHn 64

static constexpr float EPSv = 1e-5f;
// softmax in exp2 domain: scale = (1/sqrt(64)) * log2(e)
static constexpr float C_SCALE = 0.18033688011112042f;

#define GLDS16(g, l)                                                         \
    __builtin_amdgcn_global_load_lds(                                        \
        (const __attribute__((address_space(1))) void*)(g),                  \
        (__attribute__((address_space(3))) void*)(l), 16, 0, 0)

// ---------------------------------------------------------------------------
// fp32 -> bf16 conversion, all tensors fused.
// ---------------------------------------------------------------------------
__global__ __launch_bounds__(256)
void cvt_all(const float* __restrict__ x, const float* __restrict__ enc,
             const float* __restrict__ q1w, const float* __restrict__ q2w,
             const float* __restrict__ k1w, const float* __restrict__ k2w,
             const float* __restrict__ vw,  const float* __restrict__ outw,
             bf16_t* __restrict__ xb, bf16_t* __restrict__ encb,
             bf16_t* __restrict__ wq, bf16_t* __restrict__ wkv,
             bf16_t* __restrict__ wob)
{
    int idx = blockIdx.x * 256 + threadIdx.x;   // 0 .. 3670015
    const float* src; bf16_t* dst;
    if      (idx < 1048576) { src = x    + (size_t)idx * 4;              dst = xb   + (size_t)idx * 4; }
    else if (idx < 2097152) { src = enc  + (size_t)(idx - 1048576) * 4;  dst = encb + (size_t)(idx - 1048576) * 4; }
    else if (idx < 2359296) { src = q1w  + (size_t)(idx - 2097152) * 4;  dst = wq   + (size_t)(idx - 2097152) * 4; }
    else if (idx < 2621440) { src = q2w  + (size_t)(idx - 2359296) * 4;  dst = wq   + 1048576 + (size_t)(idx - 2359296) * 4; }
    else if (idx < 2883584) { src = k1w  + (size_t)(idx - 2621440) * 4;  dst = wkv  + (size_t)(idx - 2621440) * 4; }
    else if (idx < 3145728) { src = k2w  + (size_t)(idx - 2883584) * 4;  dst = wkv  + 1048576 + (size_t)(idx - 2883584) * 4; }
    else if (idx < 3407872) { src = vw   + (size_t)(idx - 3145728) * 4;  dst = wkv  + 2097152 + (size_t)(idx - 3145728) * 4; }
    else                    { src = outw + (size_t)(idx - 3407872) * 4;  dst = wob  + (size_t)(idx - 3407872) * 4; }
    float4 v = *(const float4*)src;
    bf16x4 o;
    o[0] = (bf16_t)v.x; o[1] = (bf16_t)v.y; o[2] = (bf16_t)v.z; o[3] = (bf16_t)v.w;
    *(bf16x4*)dst = o;
}

// ---------------------------------------------------------------------------
// Projection GEMM (m97 recipe, coalesced LDS epilogue) + 4x2 XCD rectangle
// (R9-measured win). XCD k owns bx in [(k&3)*10,+10) x by in [(k>>2)*16,+16):
// W/XCD = 2.5 MB (L2-resident).
// ---------------------------------------------------------------------------
__global__ __launch_bounds__(256, 4)
void gemm_proj(const bf16_t* __restrict__ xb, const bf16_t* __restrict__ encb,
               const bf16_t* __restrict__ wq, const bf16_t* __restrict__ wkv,
               const float* __restrict__ q1b, const float* __restrict__ q2b,
               const float* __restrict__ k1b, const float* __restrict__ k2b,
               const float* __restrict__ vb,
               bf16_t* __restrict__ q12, bf16_t* __restrict__ k12v)
{
    __shared__ __align__(16) bf16_t sAB[2][128 * 64];
    bf16_t* const sA = &sAB[0][0];
    bf16_t* const sB = &sAB[1][0];
    bf16_t* const sC = &sAB[0][0];      // epilogue overlay [128][128]

    // bijective 4x2 rectangle remap of flat id L (0..1279)
    const int L = blockIdx.x;
    const int xcd = L & 7, o = L >> 3;              // o in 0..159
    int bx = (xcd & 3) * 10 + (o % 10);             // 0..39
    const int blockM = ((xcd >> 2) * 16 + (o / 10)) << 7;   // by 0..31

    const bf16_t* A; const bf16_t* W; bf16_t* C; const float* bp; int blockN;
    if (bx < 16) {
        A = xb; W = wq; C = q12; blockN = bx << 7;
        bp = (blockN >> 10) ? q2b : q1b;
    } else {
        bx -= 16;
        A = encb; W = wkv; C = k12v; blockN = bx << 7;
        const int seg0 = blockN >> 10;
        bp = (seg0 == 0) ? k1b : ((seg0 == 1) ? k2b : vb);
    }

    const int tid = threadIdx.x;
    const int w = tid >> 6, lane = tid & 63;
    const int q = lane >> 4, r = lane & 15;
    const int wm = w & 1, wn = w >> 1;

    f32x4 acc[4][4];
#pragma unroll
    for (int i = 0; i < 4; ++i)
#pragma unroll
        for (int j = 0; j < 4; ++j) acc[i][j] = (f32x4){0.f, 0.f, 0.f, 0.f};

    for (int k0 = 0; k0 < 1024; k0 += 64) {
#pragma unroll
        for (int c = 0; c < 4; ++c) {
            const int s = c * 256 + tid;
            const int row = s >> 3;
            const int cg = (s & 7) ^ (row & 7);
            GLDS16(A + (size_t)(blockM + row) * 1024 + k0 + cg * 8, sA + c * 2048 + w * 512);
            GLDS16(W + (size_t)(blockN + row) * 1024 + k0 + cg * 8, sB + c * 2048 + w * 512);
        }
        __syncthreads();
#pragma unroll
        for (int ks = 0; ks < 2; ++ks) {
            bf16x8 a[4], b[4];
#pragma unroll
            for (int i = 0; i < 4; ++i) {
                const int row = wm * 64 + i * 16 + r;
                const int g = (ks * 4 + q) ^ (row & 7);
                a[i] = *(const bf16x8*)&sA[row * 64 + g * 8];
            }
#pragma unroll
            for (int j = 0; j < 4; ++j) {
                const int row = wn * 64 + j * 16 + r;
                const int g = (ks * 4 + q) ^ (row & 7);
                b[j] = *(const bf16x8*)&sB[row * 64 + g * 8];
            }
#pragma unroll
            for (int i = 0; i < 4; ++i)
#pragma unroll
                for (int j = 0; j < 4; ++j)
                    acc[i][j] = __builtin_amdgcn_mfma_f32_16x16x32_bf16(a[i], b[j], acc[i][j], 0, 0, 0);
        }
        __syncthreads();
    }

    // ---- epilogue: stage to LDS (swizzled), then coalesced 16B stores ----
#pragma unroll
    for (int j = 0; j < 4; ++j) {
        const int n = wn * 64 + j * 16 + r;             // 0..127 local
        const float bv = bp[(blockN + n) & 1023];
#pragma unroll
        for (int i = 0; i < 4; ++i) {
            f32x4 v = acc[i][j];
#pragma unroll
            for (int e = 0; e < 4; ++e) {
                const int m = wm * 64 + i * 16 + q * 4 + e;
                sC[m * 128 + (((n >> 3) ^ (m & 7)) << 3) + (n & 7)] = (bf16_t)(v[e] + bv);
            }
        }
    }
    __syncthreads();
    const int seg = blockN >> 10;
#pragma unroll
    for (int v8 = 0; v8 < 8; ++v8) {
        const int flat = v8 * 256 + tid;    // 0..2047
        const int m = flat >> 4;            // tile row
        const int nb = flat & 15;           // 16B col-block
        bf16x8 row = *(const bf16x8*)&sC[m * 128 + ((nb ^ (m & 7)) << 3)];
        const int gm = blockM + m, gn = blockN + nb * 8;
        const int bb = gm >> 10, t = gm & 1023;
        const int h = (gn >> 6) & 15, d = gn & 63;
        *(bf16x8*)&C[((((size_t)seg * 4 + bb) * 16 + h) * 1024 + t) * 64 + d] = row;
    }
}

// ---------------------------------------------------------------------------
// Output GEMM with FUSED GroupNorm on the A-operand (unchanged from R8-R10).
// ---------------------------------------------------------------------------
__global__ __launch_bounds__(256, 4)
void gemm_out_gn(const bf16_t* __restrict__ attnb, const float* __restrict__ stats,
                 const float* __restrict__ gamma, const float* __restrict__ beta,
                 const bf16_t* __restrict__ wob, const float* __restrict__ outb,
                 float* __restrict__ out)
{
    __shared__ __align__(16) bf16_t sA[64 * 64];    // 8 KB
    __shared__ __align__(16) bf16_t sB[128 * 64];   // 16 KB
    __shared__ float sCa[1024];                     // rstd*gamma per c
    __shared__ float sCb[1024];                     // beta - mu*rstd*gamma
    __shared__ float sMu[16], sRs[16];

    const int L = blockIdx.x;
    const int xcd = L & 7, kk = L >> 3;
    const int blockM = (xcd * 8 + (kk >> 3)) * 64;
    const int blockN = (kk & 7) * 128;
    const int b = blockM >> 10;

    const int tid = threadIdx.x;
    const int w = tid >> 6, lane = tid & 63;
    const int q = lane >> 4, r = lane & 15;

    // ---- per-block GN coefficient precompute ----
    if (tid < 16) {
        const int bh = b * 16 + tid;
        float s1 = 0.f, s2 = 0.f;
#pragma unroll
        for (int k = 0; k < 8; ++k) { s1 += stats[bh * 8 + k]; s2 += stats[512 + bh * 8 + k]; }
        const float mu = s1 * (1.f / 65536.f);
        const float var = s2 * (1.f / 65536.f) - mu * mu;
        sMu[tid] = mu;
        sRs[tid] = rsqrtf(var + EPSv);
    }
    __syncthreads();
#pragma unroll
    for (int u = 0; u < 4; ++u) {
        const int c = u * 256 + tid;
        const int h = c >> 6;
        const float a = sRs[h] * gamma[c];
        sCa[c] = a;
        sCb[c] = beta[c] - sMu[h] * a;
    }
    __syncthreads();

    f32x4 acc[4][2];
#pragma unroll
    for (int i = 0; i < 4; ++i)
#pragma unroll
        for (int j = 0; j < 2; ++j) acc[i][j] = (f32x4){0.f, 0.f, 0.f, 0.f};

    for (int k0 = 0; k0 < 1024; k0 += 64) {
        const int h = k0 >> 6;
        // ---- A: 64x64 with GN applied (reg-staged, swizzled ds_write) ----
#pragma unroll
        for (int c = 0; c < 2; ++c) {
            const int s = c * 256 + tid;
            const int row = s >> 3;             // 0..63
            const int cb = s & 7;
            const int t = (blockM + row) & 1023;
            bf16x8 v = *(const bf16x8*)(attnb + ((size_t)(b * 16 + h) << 16) + t * 64 + cb * 8);
            const int cbase = h * 64 + cb * 8;
            f32x4 ca0 = *(const f32x4*)&sCa[cbase];
            f32x4 ca1 = *(const f32x4*)&sCa[cbase + 4];
            f32x4 cb0 = *(const f32x4*)&sCb[cbase];
            f32x4 cb1 = *(const f32x4*)&sCb[cbase + 4];
            bf16x8 o;
#pragma unroll
            for (int i = 0; i < 4; ++i) {
                o[i]     = (bf16_t)((float)v[i]     * ca0[i] + cb0[i]);
                o[i + 4] = (bf16_t)((float)v[i + 4] * ca1[i] + cb1[i]);
            }
            *(bf16x8*)&sA[row * 64 + ((cb ^ (row & 7)) << 3)] = o;
        }
        // ---- B via GLDS16 ----
#pragma unroll
        for (int c = 0; c < 4; ++c) {
            const int s = c * 256 + tid;
            const int row = s >> 3;
            const int cg = (s & 7) ^ (row & 7);
            GLDS16(wob + (size_t)(blockN + row) * 1024 + k0 + cg * 8, sB + c * 2048 + w * 512);
        }
        __syncthreads();
#pragma unroll
        for (int ks = 0; ks < 2; ++ks) {
            bf16x8 a[4], bfr[2];
#pragma unroll
            for (int i = 0; i < 4; ++i) {
                const int row = i * 16 + r;
                const int g = (ks * 4 + q) ^ (row & 7);
                a[i] = *(const bf16x8*)&sA[row * 64 + g * 8];
            }
#pragma unroll
            for (int j = 0; j < 2; ++j) {
                const int row = w * 32 + j * 16 + r;
                const int g = (ks * 4 + q) ^ (row & 7);
                bfr[j] = *(const bf16x8*)&sB[row * 64 + g * 8];
            }
#pragma unroll
            for (int i = 0; i < 4; ++i)
#pragma unroll
                for (int j = 0; j < 2; ++j)
                    acc[i][j] = __builtin_amdgcn_mfma_f32_16x16x32_bf16(a[i], bfr[j], acc[i][j], 0, 0, 0);
        }
        __syncthreads();
    }

#pragma unroll
    for (int j = 0; j < 2; ++j) {
        const int n = blockN + w * 32 + j * 16 + r;
        const float bv = outb[n];
#pragma unroll
        for (int i = 0; i < 4; ++i) {
            f32x4 v = acc[i][j];
#pragma unroll
            for (int e = 0; e < 4; ++e) {
                const int m = blockM + i * 16 + q * 4 + e;
                out[(size_t)m * 1024 + n] = v[e] + bv;
            }
        }
    }
}

// ---------------------------------------------------------------------------
// In-register P helpers (T12): cvt_pk + permlane32_swap.
// ---------------------------------------------------------------------------
__device__ __forceinline__ unsigned cvtpk_bf16(float a, float b)
{
    unsigned r;
    asm("v_cvt_pk_bf16_f32 %0, %1, %2" : "=v"(r) : "v"(a), "v"(b));
    return r;
}

// Build the two K=16 A-fragments from the 16 per-lane P values
// (p[reg] = P[kv = (reg&3) + 8*(reg>>2) + 4*(lane>>5)][q=lane&31]).
__device__ __forceinline__ void pack_pa(const f32x16& p, bf16x8& pa0, bf16x8& pa1)
{
    unsigned a0 = cvtpk_bf16(p[0], p[1]),   b0 = cvtpk_bf16(p[4], p[5]);
    asm("v_permlane32_swap_b32 %0, %1" : "+v"(a0), "+v"(b0));
    unsigned a1 = cvtpk_bf16(p[2], p[3]),   b1 = cvtpk_bf16(p[6], p[7]);
    asm("v_permlane32_swap_b32 %0, %1" : "+v"(a1), "+v"(b1));
    pa0 = __builtin_bit_cast(bf16x8, (u32x4v){a0, a1, b0, b1});
    unsigned a2 = cvtpk_bf16(p[8], p[9]),   b2 = cvtpk_bf16(p[12], p[13]);
    asm("v_permlane32_swap_b32 %0, %1" : "+v"(a2), "+v"(b2));
    unsigned a3 = cvtpk_bf16(p[10], p[11]), b3 = cvtpk_bf16(p[14], p[15]);
    asm("v_permlane32_swap_b32 %0, %1" : "+v"(a3), "+v"(b3));
    pa1 = __builtin_bit_cast(bf16x8, (u32x4v){a2, a3, b2, b3});
}

// ---------------------------------------------------------------------------
// Dual-stream differential flash attention, 32x32 MFMA, in-register P,
// single barrier per K-tile (sVt dbuf), KVBLK=64 -- EXACT R10 code (measured
// 52.6-52.9 us, VGPR 60, passed absmax 0.0195) with ONE change:
// __launch_bounds__(512, 4) -> (512, 6): 3 blocks/CU, 24 waves/CU.
// VGPR 60 <= 85 cap with margin (R7's spill was a ~100+-reg kernel; R11's
// failure is disambiguated by this A/B: if THIS fails, (512,6) miscompiles
// and gets pinned back to 4; if it passes, R11's ones-trick was the culprit).
// Grid dim3(64, 8): x = bh (XCD-local K/V), y = qt.
// ---------------------------------------------------------------------------
__global__ __launch_bounds__(512, 6)
void diff_attn32(const bf16_t* __restrict__ q12, const bf16_t* __restrict__ k12v,
                 const float* __restrict__ lam, bf16_t* __restrict__ out,
                 float* __restrict__ stats)
{
    __shared__ __align__(16) bf16_t arena[24576];   // 48 KB
    bf16_t* const sK1 = arena;                      // [2][4096] dbuf
    bf16_t* const sK2 = arena + 8192;               // [2][4096] dbuf
    bf16_t* const sVt = arena + 16384;              // [2][4096] dbuf
    float*  const xchg = (float*)arena;             // epilogue overlay [128][64] f32
    __shared__ float sl[2][128];
    __shared__ float sred[16];

    const int tid = threadIdx.x;
    const int w = tid >> 6, lane = tid & 63;        // w 0..7
    const int st_id = w >> 2, wv = w & 3;           // stream, wave-in-stream
    const int hi = lane >> 5, lo = lane & 31;
    const int bh = blockIdx.x, qt = blockIdx.y;
    const float lamv = lam[bh & (Hn - 1)];

    const size_t HT = (size_t)TKn * DHn;            // 65536
    const bf16_t* qg  = q12 + (size_t)(st_id * 64 + bh) * HT + (size_t)qt * 128 * DHn;
    const bf16_t* k1g = k12v + (size_t)bh * HT;
    const bf16_t* k2g = k1g + 64 * HT;
    const bf16_t* vg  = k1g + 128 * HT;
    const bf16_t* const sKs = st_id ? sK2 : sK1;

    // Q fragments (B-operand, 32x32x16)
    bf16x8 fQ[4];
#pragma unroll
    for (int dk = 0; dk < 4; ++dk)
        fQ[dk] = *(const bf16x8*)(qg + (size_t)(wv * 32 + lo) * 64 + dk * 16 + hi * 8);

    f32x16 O0, O1;
#pragma unroll
    for (int e = 0; e < 16; ++e) { O0[e] = 0.f; O1[e] = 0.f; }
    float lsum = 0.f;

    // ---- prologue: stage K1[0], K2[0] and V[0] (one barrier) ----
    {
        const int row = tid >> 3;
        const int cg = (tid & 7) ^ (row & 7);
        GLDS16(k1g + row * 64 + cg * 8, sK1 + tid * 8);
        GLDS16(k2g + row * 64 + cg * 8, sK2 + tid * 8);
        const int s = tid & 63;
        bf16x8 v0 = *(const bf16x8*)(vg + (size_t)s * 64 + w * 8);
#pragma unroll
        for (int i = 0; i < 8; ++i) {
            const int d = w * 8 + i;
            sVt[d * 64 + (((s >> 3) ^ i) << 3) + (s & 7)] = v0[i];
        }
        __syncthreads();    // GLDS + ds_writes drained, all visible
    }

    for (int st = 0; st < TKn / 64; ++st) {
        const int cur = st & 1, nxt = cur ^ 1;
        bf16x8 vr;
        // ---- prefetch next tile: K via GLDS into [nxt], V into regs ----
        if (st < 15) {
            const int row = tid >> 3;
            const int cg = (tid & 7) ^ (row & 7);
            GLDS16(k1g + (size_t)(st + 1) * 4096 + row * 64 + cg * 8, sK1 + nxt * 4096 + tid * 8);
            GLDS16(k2g + (size_t)(st + 1) * 4096 + row * 64 + cg * 8, sK2 + nxt * 4096 + tid * 8);
            vr = *(const bf16x8*)(vg + (size_t)(st + 1) * 4096 + (size_t)(tid & 63) * 64 + w * 8);
        }

        const bf16_t* sKc = sKs + cur * 4096;
        const bf16_t* sVc = sVt + cur * 4096;
#pragma unroll
        for (int kb = 0; kb < 2; ++kb) {
            // ---- S = K * Q^T (swapped): C[kv][q] ----
            f32x16 S;
#pragma unroll
            for (int e = 0; e < 16; ++e) S[e] = 0.f;
            __builtin_amdgcn_s_setprio(1);
#pragma unroll
            for (int dk = 0; dk < 4; ++dk) {
                bf16x8 fk = *(const bf16x8*)&sKc[(kb * 32 + lo) * 64 + (((dk * 2 + hi) ^ (lo & 7)) << 3)];
                S = __builtin_amdgcn_mfma_f32_32x32x16_bf16(fk, fQ[dk], S, 0, 0, 0);
            }
            __builtin_amdgcn_s_setprio(0);
            // ---- softmax numerator + row-partial l ----
#pragma unroll
            for (int e = 0; e < 16; ++e) {
                S[e] = __builtin_amdgcn_exp2f(S[e] * C_SCALE);
                lsum += S[e];
            }
            // ---- P -> bf16 A-fragments, in registers ----
            bf16x8 pa0, pa1;
            pack_pa(S, pa0, pa1);
            // ---- PV ----
            const int c0 = ((kb * 4 + hi) ^ (lo & 7)) << 3;
            const int c1 = ((kb * 4 + 2 + hi) ^ (lo & 7)) << 3;
            bf16x8 fv00 = *(const bf16x8*)&sVc[(0 * 32 + lo) * 64 + c0];
            bf16x8 fv01 = *(const bf16x8*)&sVc[(0 * 32 + lo) * 64 + c1];
            bf16x8 fv10 = *(const bf16x8*)&sVc[(1 * 32 + lo) * 64 + c0];
            bf16x8 fv11 = *(const bf16x8*)&sVc[(1 * 32 + lo) * 64 + c1];
            __builtin_amdgcn_s_setprio(1);
            O0 = __builtin_amdgcn_mfma_f32_32x32x16_bf16(pa0, fv00, O0, 0, 0, 0);
            O0 = __builtin_amdgcn_mfma_f32_32x32x16_bf16(pa1, fv01, O0, 0, 0, 0);
            O1 = __builtin_amdgcn_mfma_f32_32x32x16_bf16(pa0, fv10, O1, 0, 0, 0);
            O1 = __builtin_amdgcn_mfma_f32_32x32x16_bf16(pa1, fv11, O1, 0, 0, 0);
            __builtin_amdgcn_s_setprio(0);
        }

        // ---- publish next V into the buffer nobody reads this tile ----
        if (st < 15) {
            const int s = tid & 63;
#pragma unroll
            for (int i = 0; i < 8; ++i) {
                const int d = w * 8 + i;
                sVt[nxt * 4096 + d * 64 + (((s >> 3) ^ i) << 3) + (s & 7)] = vr[i];
            }
        }
        __syncthreads();    // ONE barrier/tile: drains GLDS + publishes sVt[nxt]
    }

    // ---- row-sum l ----
    lsum += __shfl_xor(lsum, 32);
    if (hi == 0) sl[st_id][wv * 32 + lo] = lsum;

    // ---- stream 2 publishes lam * O2 / l2 into dead sK arena ----
    if (st_id == 1) {
#pragma unroll
        for (int reg = 0; reg < 16; ++reg) {
            const int t = wv * 32 + (reg & 3) + 8 * (reg >> 2) + 4 * hi;
            const float inv2 = lamv / sl[1][t];
            xchg[t * 64 + lo]      = O0[reg] * inv2;
            xchg[t * 64 + 32 + lo] = O1[reg] * inv2;
        }
    }
    __syncthreads();

    // ---- stream 1 combines, stores, emits GN partials ----
    if (st_id == 0) {
        float ssum = 0.f, ssq = 0.f;
        bf16_t* op = out + ((size_t)bh * TQn + (size_t)qt * 128) * DHn;
#pragma unroll
        for (int reg = 0; reg < 16; ++reg) {
            const int t = wv * 32 + (reg & 3) + 8 * (reg >> 2) + 4 * hi;
            const float inv1 = 1.0f / sl[0][t];
            const float o0 = O0[reg] * inv1 - xchg[t * 64 + lo];
            const float o1 = O1[reg] * inv1 - xchg[t * 64 + 32 + lo];
            op[(size_t)t * 64 + lo]      = (bf16_t)o0;
            op[(size_t)t * 64 + 32 + lo] = (bf16_t)o1;
            ssum += o0 + o1;
            ssq  += o0 * o0 + o1 * o1;
        }
#pragma unroll
        for (int d = 1; d < 64; d <<= 1) {
            ssum += __shfl_xor(ssum, d);
            ssq  += __shfl_xor(ssq, d);
        }
        if (lane == 0) { sred[wv] = ssum; sred[8 + wv] = ssq; }
    }
    __syncthreads();
    if (tid == 0) {
        stats[(bh << 3) + qt]       = sred[0] + sred[1] + sred[2] + sred[3];
        stats[512 + (bh << 3) + qt] = sred[8] + sred[9] + sred[10] + sred[11];
    }
}

// ---------------------------------------------------------------------------
extern "C" void kernel_launch(void* const* d_in, const int* in_sizes, int n_in,
                              void* d_out, int out_size, void* d_ws, size_t ws_size,
                              hipStream_t stream)
{
    const float* x    = (const float*)d_in[0];
    const float* enc  = (const float*)d_in[1];
    const float* Q1w  = (const float*)d_in[2];
    const float* Q1b  = (const float*)d_in[3];
    const float* Q2w  = (const float*)d_in[4];
    const float* Q2b  = (const float*)d_in[5];
    const float* K1w  = (const float*)d_in[6];
    const float* K1b  = (const float*)d_in[7];
    const float* K2w  = (const float*)d_in[8];
    const float* K2b  = (const float*)d_in[9];
    const float* Vw   = (const float*)d_in[10];
    const float* Vb   = (const float*)d_in[11];
    const float* lam  = (const float*)d_in[12];
    const float* gng  = (const float*)d_in[13];
    const float* gnb  = (const float*)d_in[14];
    const float* outw = (const float*)d_in[15];
    const float* outb = (const float*)d_in[16];
    float* out = (float*)d_out;

    // workspace layout (bf16 elems). Peak footprint 68 MB.
    bf16_t* xb   = (bf16_t*)d_ws;            // 4,194,304   live k1..k2
    bf16_t* encb = xb   + 4194304;           // 4,194,304   live k1..k2
    bf16_t* wq   = encb + 4194304;           // 2,097,152   live k1..k2  [Q1w|Q2w]
    bf16_t* wkv  = wq   + 2097152;           // 3,145,728   live k1..k2  [K1w|K2w|Vw]
    bf16_t* wob  = wkv  + 3145728;           // 1,048,576   live k1..k4
    bf16_t* q12  = wob  + 1048576;           // 8,388,608   live k2..k3  [2][B][H][T][D]
    bf16_t* k12v = q12  + 8388608;           // 12,582,912  live k2..k3  [3][B][H][T][D]
    bf16_t* attnb= xb;                       // alias: written k3, read k4 (xb dead)
    float*  stats= (float*)wq;               // alias: 1024 fp32, written k3, read k4 (wq dead)

    cvt_all<<<14336, 256, 0, stream>>>(x, enc, Q1w, Q2w, K1w, K2w, Vw, outw,
                                       xb, encb, wq, wkv, wob);

    gemm_proj<<<1280, 256, 0, stream>>>(xb, encb, wq, wkv,
                                        Q1b, Q2b, K1b, K2b, Vb, q12, k12v);

    diff_attn32<<<dim3(64, 8), 512, 0, stream>>>(q12, k12v, lam, attnb, stats);

    gemm_out_gn<<<512, 256, 0, stream>>>(attnb, stats, gng, gnb, wob, outb, out);
}

// Round 14
// 230.307 us; speedup vs baseline: 1.3508x; 1.3508x over previous
//
#include <hip/hip_runtime.h>
#include <cmath>

typedef __bf16 bf16_t;
typedef bf16_t bf16x8 __attribute__((ext_vector_type(8)));
typedef bf16_t bf16x4 __attribute__((ext_vector_type(4)));
typedef float  f32x4  __attribute__((ext_vector_type(4)));
typedef float  f32x16 __attribute__((ext_vector_type(16)));
typedef unsigned int u32x4v __attribute__((ext_vector_type(4)));

#define Bn  4
#define TQn 1024
#define TKn 1024
#define En  1024
#define Hn  16
#define DHn 64

static constexpr float EPSv = 1e-5f;
// softmax in exp2 domain: scale = (1/sqrt(64)) * log2(e)
static constexpr float C_SCALE = 0.18033688011112042f;

#define GLDS16(g, l)                                                         \
    __builtin_amdgcn_global_load_lds(                                        \
        (const __attribute__((address_space(1))) void*)(g),                  \
        (__attribute__((address_space(3))) void*)(l), 16, 0, 0)

// ---------------------------------------------------------------------------
// fp32 -> bf16 conversion, all tensors fused.
// ---------------------------------------------------------------------------
__global__ __launch_bounds__(256)
void cvt_all(const float* __restrict__ x, const float* __restrict__ enc,
             const float* __restrict__ q1w, const float* __restrict__ q2w,
             const float* __restrict__ k1w, const float* __restrict__ k2w,
             const float* __restrict__ vw,  const float* __restrict__ outw,
             bf16_t* __restrict__ xb, bf16_t* __restrict__ encb,
             bf16_t* __restrict__ wq, bf16_t* __restrict__ wkv,
             bf16_t* __restrict__ wob)
{
    int idx = blockIdx.x * 256 + threadIdx.x;   // 0 .. 3670015
    const float* src; bf16_t* dst;
    if      (idx < 1048576) { src = x    + (size_t)idx * 4;              dst = xb   + (size_t)idx * 4; }
    else if (idx < 2097152) { src = enc  + (size_t)(idx - 1048576) * 4;  dst = encb + (size_t)(idx - 1048576) * 4; }
    else if (idx < 2359296) { src = q1w  + (size_t)(idx - 2097152) * 4;  dst = wq   + (size_t)(idx - 2097152) * 4; }
    else if (idx < 2621440) { src = q2w  + (size_t)(idx - 2359296) * 4;  dst = wq   + 1048576 + (size_t)(idx - 2359296) * 4; }
    else if (idx < 2883584) { src = k1w  + (size_t)(idx - 2621440) * 4;  dst = wkv  + (size_t)(idx - 2621440) * 4; }
    else if (idx < 3145728) { src = k2w  + (size_t)(idx - 2883584) * 4;  dst = wkv  + 1048576 + (size_t)(idx - 2883584) * 4; }
    else if (idx < 3407872) { src = vw   + (size_t)(idx - 3145728) * 4;  dst = wkv  + 2097152 + (size_t)(idx - 3145728) * 4; }
    else                    { src = outw + (size_t)(idx - 3407872) * 4;  dst = wob  + (size_t)(idx - 3407872) * 4; }
    float4 v = *(const float4*)src;
    bf16x4 o;
    o[0] = (bf16_t)v.x; o[1] = (bf16_t)v.y; o[2] = (bf16_t)v.z; o[3] = (bf16_t)v.w;
    *(bf16x4*)dst = o;
}

// ---------------------------------------------------------------------------
// Projection GEMM (m97 recipe, coalesced LDS epilogue) + 4x2 XCD rectangle
// (R9-measured win). XCD k owns bx in [(k&3)*10,+10) x by in [(k>>2)*16,+16):
// W/XCD = 2.5 MB (L2-resident).
// R13: q12 outputs (bx<16) are pre-scaled by C_SCALE --
// exp2((Q.K)*C_SCALE) == exp2((Q*C_SCALE).K), bias included in Q -- which
// deletes the per-element C_SCALE multiply from attn's VALU-bound inner loop.
// ---------------------------------------------------------------------------
__global__ __launch_bounds__(256, 4)
void gemm_proj(const bf16_t* __restrict__ xb, const bf16_t* __restrict__ encb,
               const bf16_t* __restrict__ wq, const bf16_t* __restrict__ wkv,
               const float* __restrict__ q1b, const float* __restrict__ q2b,
               const float* __restrict__ k1b, const float* __restrict__ k2b,
               const float* __restrict__ vb,
               bf16_t* __restrict__ q12, bf16_t* __restrict__ k12v)
{
    __shared__ __align__(16) bf16_t sAB[2][128 * 64];
    bf16_t* const sA = &sAB[0][0];
    bf16_t* const sB = &sAB[1][0];
    bf16_t* const sC = &sAB[0][0];      // epilogue overlay [128][128]

    // bijective 4x2 rectangle remap of flat id L (0..1279)
    const int L = blockIdx.x;
    const int xcd = L & 7, o = L >> 3;              // o in 0..159
    int bx = (xcd & 3) * 10 + (o % 10);             // 0..39
    const int blockM = ((xcd >> 2) * 16 + (o / 10)) << 7;   // by 0..31

    const bf16_t* A; const bf16_t* W; bf16_t* C; const float* bp; int blockN;
    float pscale;
    if (bx < 16) {
        A = xb; W = wq; C = q12; blockN = bx << 7;
        bp = (blockN >> 10) ? q2b : q1b;
        pscale = C_SCALE;
    } else {
        bx -= 16;
        A = encb; W = wkv; C = k12v; blockN = bx << 7;
        const int seg0 = blockN >> 10;
        bp = (seg0 == 0) ? k1b : ((seg0 == 1) ? k2b : vb);
        pscale = 1.0f;
    }

    const int tid = threadIdx.x;
    const int w = tid >> 6, lane = tid & 63;
    const int q = lane >> 4, r = lane & 15;
    const int wm = w & 1, wn = w >> 1;

    f32x4 acc[4][4];
#pragma unroll
    for (int i = 0; i < 4; ++i)
#pragma unroll
        for (int j = 0; j < 4; ++j) acc[i][j] = (f32x4){0.f, 0.f, 0.f, 0.f};

    for (int k0 = 0; k0 < 1024; k0 += 64) {
#pragma unroll
        for (int c = 0; c < 4; ++c) {
            const int s = c * 256 + tid;
            const int row = s >> 3;
            const int cg = (s & 7) ^ (row & 7);
            GLDS16(A + (size_t)(blockM + row) * 1024 + k0 + cg * 8, sA + c * 2048 + w * 512);
            GLDS16(W + (size_t)(blockN + row) * 1024 + k0 + cg * 8, sB + c * 2048 + w * 512);
        }
        __syncthreads();
#pragma unroll
        for (int ks = 0; ks < 2; ++ks) {
            bf16x8 a[4], b[4];
#pragma unroll
            for (int i = 0; i < 4; ++i) {
                const int row = wm * 64 + i * 16 + r;
                const int g = (ks * 4 + q) ^ (row & 7);
                a[i] = *(const bf16x8*)&sA[row * 64 + g * 8];
            }
#pragma unroll
            for (int j = 0; j < 4; ++j) {
                const int row = wn * 64 + j * 16 + r;
                const int g = (ks * 4 + q) ^ (row & 7);
                b[j] = *(const bf16x8*)&sB[row * 64 + g * 8];
            }
#pragma unroll
            for (int i = 0; i < 4; ++i)
#pragma unroll
                for (int j = 0; j < 4; ++j)
                    acc[i][j] = __builtin_amdgcn_mfma_f32_16x16x32_bf16(a[i], b[j], acc[i][j], 0, 0, 0);
        }
        __syncthreads();
    }

    // ---- epilogue: stage to LDS (swizzled), then coalesced 16B stores ----
#pragma unroll
    for (int j = 0; j < 4; ++j) {
        const int n = wn * 64 + j * 16 + r;             // 0..127 local
        const float bv = bp[(blockN + n) & 1023];
#pragma unroll
        for (int i = 0; i < 4; ++i) {
            f32x4 v = acc[i][j];
#pragma unroll
            for (int e = 0; e < 4; ++e) {
                const int m = wm * 64 + i * 16 + q * 4 + e;
                sC[m * 128 + (((n >> 3) ^ (m & 7)) << 3) + (n & 7)] = (bf16_t)((v[e] + bv) * pscale);
            }
        }
    }
    __syncthreads();
    const int seg = blockN >> 10;
#pragma unroll
    for (int v8 = 0; v8 < 8; ++v8) {
        const int flat = v8 * 256 + tid;    // 0..2047
        const int m = flat >> 4;            // tile row
        const int nb = flat & 15;           // 16B col-block
        bf16x8 row = *(const bf16x8*)&sC[m * 128 + ((nb ^ (m & 7)) << 3)];
        const int gm = blockM + m, gn = blockN + nb * 8;
        const int bb = gm >> 10, t = gm & 1023;
        const int h = (gn >> 6) & 15, d = gn & 63;
        *(bf16x8*)&C[((((size_t)seg * 4 + bb) * 16 + h) * 1024 + t) * 64 + d] = row;
    }
}

// ---------------------------------------------------------------------------
// Output GEMM with FUSED GroupNorm on the A-operand (unchanged from R8-R10).
// ---------------------------------------------------------------------------
__global__ __launch_bounds__(256, 4)
void gemm_out_gn(const bf16_t* __restrict__ attnb, const float* __restrict__ stats,
                 const float* __restrict__ gamma, const float* __restrict__ beta,
                 const bf16_t* __restrict__ wob, const float* __restrict__ outb,
                 float* __restrict__ out)
{
    __shared__ __align__(16) bf16_t sA[64 * 64];    // 8 KB
    __shared__ __align__(16) bf16_t sB[128 * 64];   // 16 KB
    __shared__ float sCa[1024];                     // rstd*gamma per c
    __shared__ float sCb[1024];                     // beta - mu*rstd*gamma
    __shared__ float sMu[16], sRs[16];

    const int L = blockIdx.x;
    const int xcd = L & 7, kk = L >> 3;
    const int blockM = (xcd * 8 + (kk >> 3)) * 64;
    const int blockN = (kk & 7) * 128;
    const int b = blockM >> 10;

    const int tid = threadIdx.x;
    const int w = tid >> 6, lane = tid & 63;
    const int q = lane >> 4, r = lane & 15;

    // ---- per-block GN coefficient precompute ----
    if (tid < 16) {
        const int bh = b * 16 + tid;
        float s1 = 0.f, s2 = 0.f;
#pragma unroll
        for (int k = 0; k < 8; ++k) { s1 += stats[bh * 8 + k]; s2 += stats[512 + bh * 8 + k]; }
        const float mu = s1 * (1.f / 65536.f);
        const float var = s2 * (1.f / 65536.f) - mu * mu;
        sMu[tid] = mu;
        sRs[tid] = rsqrtf(var + EPSv);
    }
    __syncthreads();
#pragma unroll
    for (int u = 0; u < 4; ++u) {
        const int c = u * 256 + tid;
        const int h = c >> 6;
        const float a = sRs[h] * gamma[c];
        sCa[c] = a;
        sCb[c] = beta[c] - sMu[h] * a;
    }
    __syncthreads();

    f32x4 acc[4][2];
#pragma unroll
    for (int i = 0; i < 4; ++i)
#pragma unroll
        for (int j = 0; j < 2; ++j) acc[i][j] = (f32x4){0.f, 0.f, 0.f, 0.f};

    for (int k0 = 0; k0 < 1024; k0 += 64) {
        const int h = k0 >> 6;
        // ---- A: 64x64 with GN applied (reg-staged, swizzled ds_write) ----
#pragma unroll
        for (int c = 0; c < 2; ++c) {
            const int s = c * 256 + tid;
            const int row = s >> 3;             // 0..63
            const int cb = s & 7;
            const int t = (blockM + row) & 1023;
            bf16x8 v = *(const bf16x8*)(attnb + ((size_t)(b * 16 + h) << 16) + t * 64 + cb * 8);
            const int cbase = h * 64 + cb * 8;
            f32x4 ca0 = *(const f32x4*)&sCa[cbase];
            f32x4 ca1 = *(const f32x4*)&sCa[cbase + 4];
            f32x4 cb0 = *(const f32x4*)&sCb[cbase];
            f32x4 cb1 = *(const f32x4*)&sCb[cbase + 4];
            bf16x8 o;
#pragma unroll
            for (int i = 0; i < 4; ++i) {
                o[i]     = (bf16_t)((float)v[i]     * ca0[i] + cb0[i]);
                o[i + 4] = (bf16_t)((float)v[i + 4] * ca1[i] + cb1[i]);
            }
            *(bf16x8*)&sA[row * 64 + ((cb ^ (row & 7)) << 3)] = o;
        }
        // ---- B via GLDS16 ----
#pragma unroll
        for (int c = 0; c < 4; ++c) {
            const int s = c * 256 + tid;
            const int row = s >> 3;
            const int cg = (s & 7) ^ (row & 7);
            GLDS16(wob + (size_t)(blockN + row) * 1024 + k0 + cg * 8, sB + c * 2048 + w * 512);
        }
        __syncthreads();
#pragma unroll
        for (int ks = 0; ks < 2; ++ks) {
            bf16x8 a[4], bfr[2];
#pragma unroll
            for (int i = 0; i < 4; ++i) {
                const int row = i * 16 + r;
                const int g = (ks * 4 + q) ^ (row & 7);
                a[i] = *(const bf16x8*)&sA[row * 64 + g * 8];
            }
#pragma unroll
            for (int j = 0; j < 2; ++j) {
                const int row = w * 32 + j * 16 + r;
                const int g = (ks * 4 + q) ^ (row & 7);
                bfr[j] = *(const bf16x8*)&sB[row * 64 + g * 8];
            }
#pragma unroll
            for (int i = 0; i < 4; ++i)
#pragma unroll
                for (int j = 0; j < 2; ++j)
                    acc[i][j] = __builtin_amdgcn_mfma_f32_16x16x32_bf16(a[i], bfr[j], acc[i][j], 0, 0, 0);
        }
        __syncthreads();
    }

#pragma unroll
    for (int j = 0; j < 2; ++j) {
        const int n = blockN + w * 32 + j * 16 + r;
        const float bv = outb[n];
#pragma unroll
        for (int i = 0; i < 4; ++i) {
            f32x4 v = acc[i][j];
#pragma unroll
            for (int e = 0; e < 4; ++e) {
                const int m = blockM + i * 16 + q * 4 + e;
                out[(size_t)m * 1024 + n] = v[e] + bv;
            }
        }
    }
}

// ---------------------------------------------------------------------------
// In-register P helpers (T12): cvt_pk + permlane32_swap.
// ---------------------------------------------------------------------------
__device__ __forceinline__ unsigned cvtpk_bf16(float a, float b)
{
    unsigned r;
    asm("v_cvt_pk_bf16_f32 %0, %1, %2" : "=v"(r) : "v"(a), "v"(b));
    return r;
}

// Build the two K=16 A-fragments from the 16 per-lane P values
// (p[reg] = P[kv = (reg&3) + 8*(reg>>2) + 4*(lane>>5)][q=lane&31]).
__device__ __forceinline__ void pack_pa(const f32x16& p, bf16x8& pa0, bf16x8& pa1)
{
    unsigned a0 = cvtpk_bf16(p[0], p[1]),   b0 = cvtpk_bf16(p[4], p[5]);
    asm("v_permlane32_swap_b32 %0, %1" : "+v"(a0), "+v"(b0));
    unsigned a1 = cvtpk_bf16(p[2], p[3]),   b1 = cvtpk_bf16(p[6], p[7]);
    asm("v_permlane32_swap_b32 %0, %1" : "+v"(a1), "+v"(b1));
    pa0 = __builtin_bit_cast(bf16x8, (u32x4v){a0, a1, b0, b1});
    unsigned a2 = cvtpk_bf16(p[8], p[9]),   b2 = cvtpk_bf16(p[12], p[13]);
    asm("v_permlane32_swap_b32 %0, %1" : "+v"(a2), "+v"(b2));
    unsigned a3 = cvtpk_bf16(p[10], p[11]), b3 = cvtpk_bf16(p[14], p[15]);
    asm("v_permlane32_swap_b32 %0, %1" : "+v"(a3), "+v"(b3));
    pa1 = __builtin_bit_cast(bf16x8, (u32x4v){a2, a3, b2, b3});
}

// ---------------------------------------------------------------------------
// Dual-stream differential flash attention, 32x32 MFMA, in-register P,
// single barrier per K-tile (sVt dbuf), KVBLK=64 -- the R10 kernel (measured
// 52.6-52.9 us, VGPR 60, absmax 0.0195) with Q pre-scaled by C_SCALE in
// gemm_proj (removes the S*C_SCALE multiply from the VALU-bound inner loop).
// __launch_bounds__(512, 4) is PINNED: (512,6) spills even this VGPR-60
// kernel (R12 A/B: VGPR 40, 108 MB scratch, 129 us -- correct but 2.5x slow).
// The ones-trick l-reduction (R11) produced wrong results -- shelved.
// Grid dim3(64, 8): x = bh (XCD-local K/V), y = qt.
// ---------------------------------------------------------------------------
__global__ __launch_bounds__(512, 4)
void diff_attn32(const bf16_t* __restrict__ q12, const bf16_t* __restrict__ k12v,
                 const float* __restrict__ lam, bf16_t* __restrict__ out,
                 float* __restrict__ stats)
{
    __shared__ __align__(16) bf16_t arena[24576];   // 48 KB
    bf16_t* const sK1 = arena;                      // [2][4096] dbuf
    bf16_t* const sK2 = arena + 8192;               // [2][4096] dbuf
    bf16_t* const sVt = arena + 16384;              // [2][4096] dbuf
    float*  const xchg = (float*)arena;             // epilogue overlay [128][64] f32
    __shared__ float sl[2][128];
    __shared__ float sred[16];

    const int tid = threadIdx.x;
    const int w = tid >> 6, lane = tid & 63;        // w 0..7
    const int st_id = w >> 2, wv = w & 3;           // stream, wave-in-stream
    const int hi = lane >> 5, lo = lane & 31;
    const int bh = blockIdx.x, qt = blockIdx.y;
    const float lamv = lam[bh & (Hn - 1)];

    const size_t HT = (size_t)TKn * DHn;            // 65536
    const bf16_t* qg  = q12 + (size_t)(st_id * 64 + bh) * HT + (size_t)qt * 128 * DHn;
    const bf16_t* k1g = k12v + (size_t)bh * HT;
    const bf16_t* k2g = k1g + 64 * HT;
    const bf16_t* vg  = k1g + 128 * HT;
    const bf16_t* const sKs = st_id ? sK2 : sK1;

    // Q fragments (B-operand, 32x32x16); q12 is pre-scaled by C_SCALE
    bf16x8 fQ[4];
#pragma unroll
    for (int dk = 0; dk < 4; ++dk)
        fQ[dk] = *(const bf16x8*)(qg + (size_t)(wv * 32 + lo) * 64 + dk * 16 + hi * 8);

    f32x16 O0, O1;
#pragma unroll
    for (int e = 0; e < 16; ++e) { O0[e] = 0.f; O1[e] = 0.f; }
    float lsum = 0.f;

    // ---- prologue: stage K1[0], K2[0] and V[0] (one barrier) ----
    {
        const int row = tid >> 3;
        const int cg = (tid & 7) ^ (row & 7);
        GLDS16(k1g + row * 64 + cg * 8, sK1 + tid * 8);
        GLDS16(k2g + row * 64 + cg * 8, sK2 + tid * 8);
        const int s = tid & 63;
        bf16x8 v0 = *(const bf16x8*)(vg + (size_t)s * 64 + w * 8);
#pragma unroll
        for (int i = 0; i < 8; ++i) {
            const int d = w * 8 + i;
            sVt[d * 64 + (((s >> 3) ^ i) << 3) + (s & 7)] = v0[i];
        }
        __syncthreads();    // GLDS + ds_writes drained, all visible
    }

    for (int st = 0; st < TKn / 64; ++st) {
        const int cur = st & 1, nxt = cur ^ 1;
        bf16x8 vr;
        // ---- prefetch next tile: K via GLDS into [nxt], V into regs ----
        if (st < 15) {
            const int row = tid >> 3;
            const int cg = (tid & 7) ^ (row & 7);
            GLDS16(k1g + (size_t)(st + 1) * 4096 + row * 64 + cg * 8, sK1 + nxt * 4096 + tid * 8);
            GLDS16(k2g + (size_t)(st + 1) * 4096 + row * 64 + cg * 8, sK2 + nxt * 4096 + tid * 8);
            vr = *(const bf16x8*)(vg + (size_t)(st + 1) * 4096 + (size_t)(tid & 63) * 64 + w * 8);
        }

        const bf16_t* sKc = sKs + cur * 4096;
        const bf16_t* sVc = sVt + cur * 4096;
#pragma unroll
        for (int kb = 0; kb < 2; ++kb) {
            // ---- S = K * Q^T (swapped): C[kv][q]; Q pre-scaled ----
            f32x16 S;
#pragma unroll
            for (int e = 0; e < 16; ++e) S[e] = 0.f;
            __builtin_amdgcn_s_setprio(1);
#pragma unroll
            for (int dk = 0; dk < 4; ++dk) {
                bf16x8 fk = *(const bf16x8*)&sKc[(kb * 32 + lo) * 64 + (((dk * 2 + hi) ^ (lo & 7)) << 3)];
                S = __builtin_amdgcn_mfma_f32_32x32x16_bf16(fk, fQ[dk], S, 0, 0, 0);
            }
            __builtin_amdgcn_s_setprio(0);
            // ---- softmax numerator + row-partial l (scale pre-folded) ----
#pragma unroll
            for (int e = 0; e < 16; ++e) {
                S[e] = __builtin_amdgcn_exp2f(S[e]);
                lsum += S[e];
            }
            // ---- P -> bf16 A-fragments, in registers ----
            bf16x8 pa0, pa1;
            pack_pa(S, pa0, pa1);
            // ---- PV ----
            const int c0 = ((kb * 4 + hi) ^ (lo & 7)) << 3;
            const int c1 = ((kb * 4 + 2 + hi) ^ (lo & 7)) << 3;
            bf16x8 fv00 = *(const bf16x8*)&sVc[(0 * 32 + lo) * 64 + c0];
            bf16x8 fv01 = *(const bf16x8*)&sVc[(0 * 32 + lo) * 64 + c1];
            bf16x8 fv10 = *(const bf16x8*)&sVc[(1 * 32 + lo) * 64 + c0];
            bf16x8 fv11 = *(const bf16x8*)&sVc[(1 * 32 + lo) * 64 + c1];
            __builtin_amdgcn_s_setprio(1);
            O0 = __builtin_amdgcn_mfma_f32_32x32x16_bf16(pa0, fv00, O0, 0, 0, 0);
            O0 = __builtin_amdgcn_mfma_f32_32x32x16_bf16(pa1, fv01, O0, 0, 0, 0);
            O1 = __builtin_amdgcn_mfma_f32_32x32x16_bf16(pa0, fv10, O1, 0, 0, 0);
            O1 = __builtin_amdgcn_mfma_f32_32x32x16_bf16(pa1, fv11, O1, 0, 0, 0);
            __builtin_amdgcn_s_setprio(0);
        }

        // ---- publish next V into the buffer nobody reads this tile ----
        if (st < 15) {
            const int s = tid & 63;
#pragma unroll
            for (int i = 0; i < 8; ++i) {
                const int d = w * 8 + i;
                sVt[nxt * 4096 + d * 64 + (((s >> 3) ^ i) << 3) + (s & 7)] = vr[i];
            }
        }
        __syncthreads();    // ONE barrier/tile: drains GLDS + publishes sVt[nxt]
    }

    // ---- row-sum l ----
    lsum += __shfl_xor(lsum, 32);
    if (hi == 0) sl[st_id][wv * 32 + lo] = lsum;

    // ---- stream 2 publishes lam * O2 / l2 into dead sK arena ----
    if (st_id == 1) {
#pragma unroll
        for (int reg = 0; reg < 16; ++reg) {
            const int t = wv * 32 + (reg & 3) + 8 * (reg >> 2) + 4 * hi;
            const float inv2 = lamv / sl[1][t];
            xchg[t * 64 + lo]      = O0[reg] * inv2;
            xchg[t * 64 + 32 + lo] = O1[reg] * inv2;
        }
    }
    __syncthreads();

    // ---- stream 1 combines, stores, emits GN partials ----
    if (st_id == 0) {
        float ssum = 0.f, ssq = 0.f;
        bf16_t* op = out + ((size_t)bh * TQn + (size_t)qt * 128) * DHn;
#pragma unroll
        for (int reg = 0; reg < 16; ++reg) {
            const int t = wv * 32 + (reg & 3) + 8 * (reg >> 2) + 4 * hi;
            const float inv1 = 1.0f / sl[0][t];
            const float o0 = O0[reg] * inv1 - xchg[t * 64 + lo];
            const float o1 = O1[reg] * inv1 - xchg[t * 64 + 32 + lo];
            op[(size_t)t * 64 + lo]      = (bf16_t)o0;
            op[(size_t)t * 64 + 32 + lo] = (bf16_t)o1;
            ssum += o0 + o1;
            ssq  += o0 * o0 + o1 * o1;
        }
#pragma unroll
        for (int d = 1; d < 64; d <<= 1) {
            ssum += __shfl_xor(ssum, d);
            ssq  += __shfl_xor(ssq, d);
        }
        if (lane == 0) { sred[wv] = ssum; sred[8 + wv] = ssq; }
    }
    __syncthreads();
    if (tid == 0) {
        stats[(bh << 3) + qt]       = sred[0] + sred[1] + sred[2] + sred[3];
        stats[512 + (bh << 3) + qt] = sred[8] + sred[9] + sred[10] + sred[11];
    }
}

// ---------------------------------------------------------------------------
extern "C" void kernel_launch(void* const* d_in, const int* in_sizes, int n_in,
                              void* d_out, int out_size, void* d_ws, size_t ws_size,
                              hipStream_t stream)
{
    const float* x    = (const float*)d_in[0];
    const float* enc  = (const float*)d_in[1];
    const float* Q1w  = (const float*)d_in[2];
    const float* Q1b  = (const float*)d_in[3];
    const float* Q2w  = (const float*)d_in[4];
    const float* Q2b  = (const float*)d_in[5];
    const float* K1w  = (const float*)d_in[6];
    const float* K1b  = (const float*)d_in[7];
    const float* K2w  = (const float*)d_in[8];
    const float* K2b  = (const float*)d_in[9];
    const float* Vw   = (const float*)d_in[10];
    const float* Vb   = (const float*)d_in[11];
    const float* lam  = (const float*)d_in[12];
    const float* gng  = (const float*)d_in[13];
    const float* gnb  = (const float*)d_in[14];
    const float* outw = (const float*)d_in[15];
    const float* outb = (const float*)d_in[16];
    float* out = (float*)d_out;

    // workspace layout (bf16 elems). Peak footprint 68 MB.
    bf16_t* xb   = (bf16_t*)d_ws;            // 4,194,304   live k1..k2
    bf16_t* encb = xb   + 4194304;           // 4,194,304   live k1..k2
    bf16_t* wq   = encb + 4194304;           // 2,097,152   live k1..k2  [Q1w|Q2w]
    bf16_t* wkv  = wq   + 2097152;           // 3,145,728   live k1..k2  [K1w|K2w|Vw]
    bf16_t* wob  = wkv  + 3145728;           // 1,048,576   live k1..k4
    bf16_t* q12  = wob  + 1048576;           // 8,388,608   live k2..k3  [2][B][H][T][D]
    bf16_t* k12v = q12  + 8388608;           // 12,582,912  live k2..k3  [3][B][H][T][D]
    bf16_t* attnb= xb;                       // alias: written k3, read k4 (xb dead)
    float*  stats= (float*)wq;               // alias: 1024 fp32, written k3, read k4 (wq dead)

    cvt_all<<<14336, 256, 0, stream>>>(x, enc, Q1w, Q2w, K1w, K2w, Vw, outw,
                                       xb, encb, wq, wkv, wob);

    gemm_proj<<<1280, 256, 0, stream>>>(xb, encb, wq, wkv,
                                        Q1b, Q2b, K1b, K2b, Vb, q12, k12v);

    diff_attn32<<<dim3(64, 8), 512, 0, stream>>>(q12, k12v, lam, attnb, stats);

    gemm_out_gn<<<512, 256, 0, stream>>>(attnb, stats, gng, gnb, wob, outb, out);
}